// Round 3
// baseline (383.543 us; speedup 1.0000x reference)
//
#include <hip/hip_runtime.h>

typedef unsigned short u16;
typedef short bf16x8 __attribute__((ext_vector_type(8)));
typedef short short4v __attribute__((ext_vector_type(4)));
typedef float floatx4 __attribute__((ext_vector_type(4)));

#define OUT_CTX 16777216           // 2*128*65536 attention elems
#define OUT_CLS (OUT_CTX + 512)

__device__ __forceinline__ u16 f2b(float f) {           // fp32 -> bf16 RNE
  unsigned int u = __float_as_uint(f);
  u += 0x7fffu + ((u >> 16) & 1u);
  return (u16)(u >> 16);
}
__device__ __forceinline__ float b2f(u16 b) { return __uint_as_float(((unsigned int)b) << 16); }

__device__ __forceinline__ bf16x8 pack8(const float* p) { // 8 consecutive f32 -> bf16x8
  float4 a = *(const float4*)p;
  float4 b = *(const float4*)(p + 4);
  bf16x8 r;
  r[0] = (short)f2b(a.x); r[1] = (short)f2b(a.y); r[2] = (short)f2b(a.z); r[3] = (short)f2b(a.w);
  r[4] = (short)f2b(b.x); r[5] = (short)f2b(b.y); r[6] = (short)f2b(b.z); r[7] = (short)f2b(b.w);
  return r;
}

__device__ __forceinline__ float dot4(float4 a, float4 b) {
  return a.x * b.x + a.y * b.y + a.z * b.z + a.w * b.w;
}

// ---- kA: K/V projection + exp + context/S accumulation.
//      512 blocks x 4 tiles of 64 cols. Swapped GEMM1 (A = x-tile, B = W rows):
//      C-fragment rows land on l -> ev epilogue writes are ds_write_b64,
//      S partials come out lane-local (reduced with 2 shfl at kernel end).
//      Accumulates into 4 pre-zeroed slots (memset before launch); CLS
//      contributions are folded into kB's reads, not initialized here.
__global__ __launch_bounds__(256) void kA(
    const float* __restrict__ x, const float* __restrict__ Wk,
    const float* __restrict__ bk, const float* __restrict__ Wv,
    const float* __restrict__ bv, float* __restrict__ S2,
    float* __restrict__ Cnum2) {
  __shared__ __align__(16) u16 xT[64][136];     // [l][ch] bf16
  __shared__ __align__(16) u16 ev[256][72];     // rows 0..127 E, 128..255 V
  const int t = threadIdx.x;
  const int w = t >> 6, lane = t & 63;
  const int quad = lane >> 4, lm = lane & 15;
  const int bid = blockIdx.x;
  const int n = bid >> 8;                       // 512 blocks: 256 per batch
  const int l0base = (bid & 255) << 8;          // 256 cols per block
  const int slot = bid & 3;                     // 4 atomic slots
  const int sc = t >> 4, sl4 = t & 15;

  float4 pf[8];
  #pragma unroll
  for (int i = 0; i < 8; ++i)
    pf[i] = *(const float4*)(x + (((size_t)(n * 128 + sc * 8 + i)) << 16) + l0base + sl4 * 4);

  // W fragments as MFMA B-operand: nt 0,1 = Wk rows {w*32, w*32+16}+lm; nt 2,3 = Wv
  bf16x8 wf[4][4];
  #pragma unroll
  for (int nt = 0; nt < 4; ++nt) {
    const float* W = (nt < 2) ? Wk : Wv;
    int row = w * 32 + (nt & 1) * 16 + lm;
    #pragma unroll
    for (int ks = 0; ks < 4; ++ks)
      wf[nt][ks] = pack8(W + row * 128 + ks * 32 + quad * 8);
  }
  float biasE[2] = { bk[w * 32 + lm], bk[w * 32 + 16 + lm] };
  float biasV[2] = { bv[w * 32 + lm], bv[w * 32 + 16 + lm] };

  floatx4 z4 = {0.f, 0.f, 0.f, 0.f};
  floatx4 cacc[2] = {z4, z4};                   // context acc (2 heads per wave)
  float sacc[2] = {0.f, 0.f};                   // S partials, lane-local

  for (int tile = 0; tile < 4; ++tile) {
    const float* pff = (const float*)pf;
    #pragma unroll
    for (int r = 0; r < 4; ++r) {
      bf16x8 vx;
      #pragma unroll
      for (int i = 0; i < 8; ++i) vx[i] = (short)f2b(pff[i * 4 + r]);
      *(bf16x8*)&xT[sl4 * 4 + r][sc * 8] = vx;  // ds_write_b128
    }
    if (tile < 3) {
      int l0n = l0base + (tile + 1) * 64;
      #pragma unroll
      for (int i = 0; i < 8; ++i)
        pf[i] = *(const float4*)(x + (((size_t)(n * 128 + sc * 8 + i)) << 16) + l0n + sl4 * 4);
    }
    __syncthreads();                            // A: xT ready

    floatx4 acc[4][4];
    #pragma unroll
    for (int mt = 0; mt < 4; ++mt)
      #pragma unroll
      for (int nt = 0; nt < 4; ++nt) acc[mt][nt] = z4;

    #pragma unroll
    for (int mt = 0; mt < 4; ++mt)
      #pragma unroll
      for (int ks = 0; ks < 4; ++ks) {
        bf16x8 xa = *(const bf16x8*)&xT[mt * 16 + lm][ks * 32 + quad * 8];
        #pragma unroll
        for (int nt = 0; nt < 4; ++nt)
          acc[mt][nt] = __builtin_amdgcn_mfma_f32_16x16x32_bf16(xa, wf[nt][ks], acc[mt][nt], 0, 0, 0);
      }
    __syncthreads();                            // B: xT consumed, next stores safe

    // epilogue: D[m=l][n=ch]; ch = w*32+nt*16+lm, l = mt*16+quad*4+j -> b64 writes
    #pragma unroll
    for (int nt = 0; nt < 2; ++nt)
      #pragma unroll
      for (int mt = 0; mt < 4; ++mt) {
        short4v p;
        #pragma unroll
        for (int j = 0; j < 4; ++j) {
          float v = __expf(acc[mt][nt][j] + biasE[nt]);
          u16 b = f2b(v);
          sacc[nt] += b2f(b);
          p[j] = (short)b;
        }
        *(short4v*)&ev[w * 32 + nt * 16 + lm][mt * 16 + quad * 4] = p;
      }
    #pragma unroll
    for (int nt = 0; nt < 2; ++nt)
      #pragma unroll
      for (int mt = 0; mt < 4; ++mt) {
        short4v p;
        #pragma unroll
        for (int j = 0; j < 4; ++j)
          p[j] = (short)f2b(acc[mt][nt + 2][j] + biasV[nt]);
        *(short4v*)&ev[128 + w * 32 + nt * 16 + lm][mt * 16 + quad * 4] = p;
      }

    // context MFMAs: read ONLY this wave's own ev rows (same-wave DS order)
    #pragma unroll
    for (int hh = 0; hh < 2; ++hh) {
      int h = w * 2 + hh;
      #pragma unroll
      for (int ks = 0; ks < 2; ++ks) {
        bf16x8 aE = *(const bf16x8*)&ev[h * 16 + lm][ks * 32 + quad * 8];
        bf16x8 bV = *(const bf16x8*)&ev[128 + h * 16 + lm][ks * 32 + quad * 8];
        cacc[hh] = __builtin_amdgcn_mfma_f32_16x16x32_bf16(aE, bV, cacc[hh], 0, 0, 0);
      }
    }
  }

  float* Cn = Cnum2 + slot * 4096;
  #pragma unroll
  for (int hh = 0; hh < 2; ++hh) {
    int h = w * 2 + hh;
    #pragma unroll
    for (int j = 0; j < 4; ++j)
      atomicAdd(&Cn[((n * 8 + h) * 16 + quad * 4 + j) * 16 + lm], cacc[hh][j]);
  }
  #pragma unroll
  for (int nt = 0; nt < 2; ++nt) {
    float s = sacc[nt];
    s += __shfl_xor(s, 16);
    s += __shfl_xor(s, 32);
    if (quad == 0)
      atomicAdd(&S2[slot * 256 + n * 128 + w * 32 + nt * 16 + lm], s);
  }
}

// ---- kB: out = M * softmax_q(Wq x + bq) + br, with M = Wr * ctx built per block.
//      1024 blocks x 2 tiles of 64 cols. ctx LDS buffer is union'd with qT
//      (ctx only needed in prologue) -> LDS 34816 B -> 4 blocks/CU; grid 1024
//      fills that capacity. CLS contributions folded into the ctx reads.
//      Blocks 0 and 512 also emit context_last + CLS_out.
__global__ __launch_bounds__(256, 4) void kB(
    const float* __restrict__ x, const float* __restrict__ CLS,
    const float* __restrict__ Wq, const float* __restrict__ bq,
    const float* __restrict__ Wr, const float* __restrict__ br,
    const float* __restrict__ S2, const float* __restrict__ Cnum2,
    float* __restrict__ out) {
  __shared__ __align__(16) u16 xT[64][136];     // [l][ch] bf16, 17408 B
  __shared__ __align__(16) u16 ubuf[64 * 136];  // prologue: f32 ctxn[4096]; main: qT
  const int t = threadIdx.x;
  const int w = t >> 6, lane = t & 63;
  const int quad = lane >> 4, lm = lane & 15;
  const int bid = blockIdx.x;
  const int n = bid >> 9;                       // 1024 blocks: 512 per batch
  const int l0base = (bid & 511) << 7;          // 128 cols per block
  const int sc = t >> 4, sl4 = t & 15;

  float4 pf[8];
  #pragma unroll
  for (int i = 0; i < 8; ++i)
    pf[i] = *(const float4*)(x + (((size_t)(n * 128 + sc * 8 + i)) << 16) + l0base + sl4 * 4);

  bf16x8 wq[2][4];
  #pragma unroll
  for (int mt = 0; mt < 2; ++mt) {
    int row = (w * 2 + mt) * 16 + lm;
    #pragma unroll
    for (int ks = 0; ks < 4; ++ks)
      wq[mt][ks] = pack8(Wq + row * 128 + ks * 32 + quad * 8);
  }
  float bqv[2][4], brv[2][4];
  #pragma unroll
  for (int mt = 0; mt < 2; ++mt)
    #pragma unroll
    for (int j = 0; j < 4; ++j) {
      bqv[mt][j] = bq[(w * 2 + mt) * 16 + quad * 4 + j];
      brv[mt][j] = br[(w * 2 + mt) * 16 + quad * 4 + j];
    }

  // stage ctx = (sum Cnum slots + CLS num) / (sum S slots + CLS den) into LDS
  float* ctxn = (float*)ubuf;                   // [h*16+k][v] f32, this block's n
  {
    int hk = t >> 1, v0 = (t & 1) * 8;          // hk 0..127, v0 0 or 8
    int hbase = hk & 0x70;                      // h*16
    float ek[4];
    float den = 0.f;
    #pragma unroll
    for (int j = 0; j < 4; ++j) {
      ek[j] = __expf(CLS[(n * 128 + hk) * 4 + j]);
      den += ek[j];
    }
    #pragma unroll
    for (int s = 0; s < 4; ++s) den += S2[s * 256 + n * 128 + hk];
    float inv = 1.f / den;
    float vv[8];
    #pragma unroll
    for (int i = 0; i < 8; ++i) {
      int v = v0 + i;
      float num = 0.f;
      #pragma unroll
      for (int s = 0; s < 4; ++s) num += Cnum2[s * 4096 + (n * 128 + hk) * 16 + v];
      #pragma unroll
      for (int j = 0; j < 4; ++j) num += ek[j] * CLS[(n * 128 + hbase + v) * 4 + j];
      vv[i] = num * inv;
    }
    float4 a = {vv[0], vv[1], vv[2], vv[3]}, b = {vv[4], vv[5], vv[6], vv[7]};
    *(float4*)&ctxn[hk * 16 + v0] = a;
    *(float4*)&ctxn[hk * 16 + v0 + 4] = b;
  }
  __syncthreads();                              // ctxn ready

  // blocks 0 / 512: emit context_last + CLS_out for their n (head 7)
  if ((bid & 511) == 0) {
    {
      int kc = t >> 4, vc = t & 15;             // all 256 threads
      out[OUT_CTX + n * 256 + t] = ctxn[(112 + kc) * 16 + vc];
    }
    if (t < 64) {
      int vc = t >> 2, j = t & 3;
      float den = 0.f, num = 0.f;
      #pragma unroll
      for (int kc = 0; kc < 16; ++kc) {
        float e_ = __expf(CLS[(n * 128 + 112 + kc) * 4 + j]);
        den += e_;
        num += e_ * ctxn[(112 + kc) * 16 + vc];
      }
      out[OUT_CLS + n * 64 + t] = num / den;
    }
  }

  // M-build: mA[mt][ks] = A-frag of M[o][cc] = sum_v Wr[o][h*16+v]*ctx[h][cc&15][v]
  bf16x8 mA[2][4];
  for (int ks = 0; ks < 4; ++ks) {
    int h = 2 * ks + (quad >> 1);
    float4 wrv[2][4];
    #pragma unroll
    for (int mt = 0; mt < 2; ++mt) {
      const float* wp = Wr + ((w * 2 + mt) * 16 + lm) * 128 + h * 16;
      #pragma unroll
      for (int q4 = 0; q4 < 4; ++q4) wrv[mt][q4] = *(const float4*)(wp + q4 * 4);
    }
    short mr0[8], mr1[8];
    #pragma unroll
    for (int jj = 0; jj < 8; ++jj) {
      int k = (quad & 1) * 8 + jj;
      const float4* cp = (const float4*)&ctxn[(h * 16 + k) * 16];
      float4 c0 = cp[0], c1 = cp[1], c2 = cp[2], c3 = cp[3];
      float m0 = dot4(wrv[0][0], c0) + dot4(wrv[0][1], c1) + dot4(wrv[0][2], c2) + dot4(wrv[0][3], c3);
      float m1 = dot4(wrv[1][0], c0) + dot4(wrv[1][1], c1) + dot4(wrv[1][2], c2) + dot4(wrv[1][3], c3);
      mr0[jj] = (short)f2b(m0);
      mr1[jj] = (short)f2b(m1);
    }
    mA[0][ks] = *(bf16x8*)mr0;
    mA[1][ks] = *(bf16x8*)mr1;
  }

  // main loop; tile-0 barrier A orders all ctxn reads before qT reuses the space
  u16 (*qT)[136] = (u16 (*)[136])ubuf;
  floatx4 z4 = {0.f, 0.f, 0.f, 0.f};
  for (int tile = 0; tile < 2; ++tile) {
    int l0 = l0base + tile * 64;
    const float* pff = (const float*)pf;
    #pragma unroll
    for (int r = 0; r < 4; ++r) {
      bf16x8 vx;
      #pragma unroll
      for (int i = 0; i < 8; ++i) vx[i] = (short)f2b(pff[i * 4 + r]);
      *(bf16x8*)&xT[sl4 * 4 + r][sc * 8] = vx;
    }
    if (tile < 1) {
      #pragma unroll
      for (int i = 0; i < 8; ++i)
        pf[i] = *(const float4*)(x + (((size_t)(n * 128 + sc * 8 + i)) << 16) + l0base + 64 + sl4 * 4);
    }
    __syncthreads();                            // A: xT RAW + ubuf WAR

    floatx4 acc[2][4];
    #pragma unroll
    for (int mt = 0; mt < 2; ++mt)
      #pragma unroll
      for (int nt = 0; nt < 4; ++nt) acc[mt][nt] = z4;

    #pragma unroll
    for (int nt = 0; nt < 4; ++nt)
      #pragma unroll
      for (int ks = 0; ks < 4; ++ks) {
        bf16x8 b = *(const bf16x8*)&xT[nt * 16 + lm][ks * 32 + quad * 8];
        #pragma unroll
        for (int mt = 0; mt < 2; ++mt)
          acc[mt][nt] = __builtin_amdgcn_mfma_f32_16x16x32_bf16(wq[mt][ks], b, acc[mt][nt], 0, 0, 0);
      }

    // per-column softmax over the 16 channels of each head (wave-local)
    #pragma unroll
    for (int mt = 0; mt < 2; ++mt) {
      int h = w * 2 + mt;
      #pragma unroll
      for (int nt = 0; nt < 4; ++nt) {
        float e[4];
        float ssum = 0.f;
        #pragma unroll
        for (int j = 0; j < 4; ++j) {
          e[j] = __expf(acc[mt][nt][j] + bqv[mt][j]);
          ssum += e[j];
        }
        ssum += __shfl_xor(ssum, 16);
        ssum += __shfl_xor(ssum, 32);
        float inv = 1.f / ssum;
        short4v p;
        #pragma unroll
        for (int j = 0; j < 4; ++j) p[j] = (short)f2b(e[j] * inv);
        *(short4v*)&qT[nt * 16 + lm][h * 16 + quad * 4] = p;
      }
    }
    __syncthreads();                            // B: all heads' q channels ready

    floatx4 acc2[2][4];
    #pragma unroll
    for (int mt = 0; mt < 2; ++mt)
      #pragma unroll
      for (int nt = 0; nt < 4; ++nt) acc2[mt][nt] = z4;

    #pragma unroll
    for (int nt = 0; nt < 4; ++nt)
      #pragma unroll
      for (int ks = 0; ks < 4; ++ks) {
        bf16x8 b = *(const bf16x8*)&qT[nt * 16 + lm][ks * 32 + quad * 8];
        #pragma unroll
        for (int mt = 0; mt < 2; ++mt)
          acc2[mt][nt] = __builtin_amdgcn_mfma_f32_16x16x32_bf16(mA[mt][ks], b, acc2[mt][nt], 0, 0, 0);
      }

    #pragma unroll
    for (int mt = 0; mt < 2; ++mt)
      #pragma unroll
      for (int j = 0; j < 4; ++j) {
        int R = (w * 2 + mt) * 16 + quad * 4 + j;
        #pragma unroll
        for (int nt = 0; nt < 4; ++nt)
          out[(((size_t)(n * 128 + R)) << 16) + l0 + nt * 16 + lm] = acc2[mt][nt][j] + brv[mt][j];
      }
  }
}

extern "C" void kernel_launch(void* const* d_in, const int* in_sizes, int n_in,
                              void* d_out, int out_size, void* d_ws, size_t ws_size,
                              hipStream_t stream) {
  const float* x   = (const float*)d_in[0];
  const float* CLS = (const float*)d_in[1];
  const float* Wk  = (const float*)d_in[2];
  const float* bk  = (const float*)d_in[3];
  const float* Wq  = (const float*)d_in[4];
  const float* bq  = (const float*)d_in[5];
  const float* Wv  = (const float*)d_in[6];
  const float* bv  = (const float*)d_in[7];
  const float* Wr  = (const float*)d_in[8];
  const float* br  = (const float*)d_in[9];
  float* out = (float*)d_out;
  char* ws = (char*)d_ws;
  float* S2    = (float*)(ws + 0);        // 4 slots x 256 f32  = 4096 B
  float* Cnum2 = (float*)(ws + 4096);     // 4 slots x 4096 f32 = 65536 B

  hipMemsetAsync(ws, 0, 69632, stream);
  kA<<<512, 256, 0, stream>>>(x, Wk, bk, Wv, bv, S2, Cnum2);
  kB<<<1024, 256, 0, stream>>>(x, CLS, Wq, bq, Wr, br, S2, Cnum2, out);
}

// Round 4
// 196.587 us; speedup vs baseline: 1.9510x; 1.9510x over previous
//
#include <hip/hip_runtime.h>

typedef unsigned short u16;
typedef short bf16x8 __attribute__((ext_vector_type(8)));
typedef short short4v __attribute__((ext_vector_type(4)));
typedef float floatx4 __attribute__((ext_vector_type(4)));

#define OUT_CTX 16777216           // 2*128*65536 attention elems
#define OUT_CLS (OUT_CTX + 512)

__device__ __forceinline__ u16 f2b(float f) {           // fp32 -> bf16 RNE
  unsigned int u = __float_as_uint(f);
  u += 0x7fffu + ((u >> 16) & 1u);
  return (u16)(u >> 16);
}
__device__ __forceinline__ float b2f(u16 b) { return __uint_as_float(((unsigned int)b) << 16); }

__device__ __forceinline__ bf16x8 pack8(const float* p) { // 8 consecutive f32 -> bf16x8
  float4 a = *(const float4*)p;
  float4 b = *(const float4*)(p + 4);
  bf16x8 r;
  r[0] = (short)f2b(a.x); r[1] = (short)f2b(a.y); r[2] = (short)f2b(a.z); r[3] = (short)f2b(a.w);
  r[4] = (short)f2b(b.x); r[5] = (short)f2b(b.y); r[6] = (short)f2b(b.z); r[7] = (short)f2b(b.w);
  return r;
}

__device__ __forceinline__ float dot4(float4 a, float4 b) {
  return a.x * b.x + a.y * b.y + a.z * b.z + a.w * b.w;
}

// ---- kA: K/V projection + exp + context/S accumulation.
//      512 blocks x 4 tiles of 64 cols. Swapped GEMM1 (A = x-tile, B = W rows):
//      C-fragment rows land on l -> ev epilogue writes are ds_write_b64,
//      S partials come out lane-local (reduced with 2 shfl at kernel end).
//      Accumulates into 4 pre-zeroed slots (memset before launch); CLS
//      contributions are folded into kB's reads, not initialized here.
__global__ __launch_bounds__(256) void kA(
    const float* __restrict__ x, const float* __restrict__ Wk,
    const float* __restrict__ bk, const float* __restrict__ Wv,
    const float* __restrict__ bv, float* __restrict__ S2,
    float* __restrict__ Cnum2) {
  __shared__ __align__(16) u16 xT[64][136];     // [l][ch] bf16
  __shared__ __align__(16) u16 ev[256][72];     // rows 0..127 E, 128..255 V
  const int t = threadIdx.x;
  const int w = t >> 6, lane = t & 63;
  const int quad = lane >> 4, lm = lane & 15;
  const int bid = blockIdx.x;
  const int n = bid >> 8;                       // 512 blocks: 256 per batch
  const int l0base = (bid & 255) << 8;          // 256 cols per block
  const int slot = bid & 3;                     // 4 atomic slots
  const int sc = t >> 4, sl4 = t & 15;

  float4 pf[8];
  #pragma unroll
  for (int i = 0; i < 8; ++i)
    pf[i] = *(const float4*)(x + (((size_t)(n * 128 + sc * 8 + i)) << 16) + l0base + sl4 * 4);

  // W fragments as MFMA B-operand: nt 0,1 = Wk rows {w*32, w*32+16}+lm; nt 2,3 = Wv
  bf16x8 wf[4][4];
  #pragma unroll
  for (int nt = 0; nt < 4; ++nt) {
    const float* W = (nt < 2) ? Wk : Wv;
    int row = w * 32 + (nt & 1) * 16 + lm;
    #pragma unroll
    for (int ks = 0; ks < 4; ++ks)
      wf[nt][ks] = pack8(W + row * 128 + ks * 32 + quad * 8);
  }
  float biasE[2] = { bk[w * 32 + lm], bk[w * 32 + 16 + lm] };
  float biasV[2] = { bv[w * 32 + lm], bv[w * 32 + 16 + lm] };

  floatx4 z4 = {0.f, 0.f, 0.f, 0.f};
  floatx4 cacc[2] = {z4, z4};                   // context acc (2 heads per wave)
  float sacc[2] = {0.f, 0.f};                   // S partials, lane-local

  for (int tile = 0; tile < 4; ++tile) {
    const float* pff = (const float*)pf;
    #pragma unroll
    for (int r = 0; r < 4; ++r) {
      bf16x8 vx;
      #pragma unroll
      for (int i = 0; i < 8; ++i) vx[i] = (short)f2b(pff[i * 4 + r]);
      *(bf16x8*)&xT[sl4 * 4 + r][sc * 8] = vx;  // ds_write_b128
    }
    if (tile < 3) {
      int l0n = l0base + (tile + 1) * 64;
      #pragma unroll
      for (int i = 0; i < 8; ++i)
        pf[i] = *(const float4*)(x + (((size_t)(n * 128 + sc * 8 + i)) << 16) + l0n + sl4 * 4);
    }
    __syncthreads();                            // A: xT ready

    floatx4 acc[4][4];
    #pragma unroll
    for (int mt = 0; mt < 4; ++mt)
      #pragma unroll
      for (int nt = 0; nt < 4; ++nt) acc[mt][nt] = z4;

    #pragma unroll
    for (int mt = 0; mt < 4; ++mt)
      #pragma unroll
      for (int ks = 0; ks < 4; ++ks) {
        bf16x8 xa = *(const bf16x8*)&xT[mt * 16 + lm][ks * 32 + quad * 8];
        #pragma unroll
        for (int nt = 0; nt < 4; ++nt)
          acc[mt][nt] = __builtin_amdgcn_mfma_f32_16x16x32_bf16(xa, wf[nt][ks], acc[mt][nt], 0, 0, 0);
      }
    __syncthreads();                            // B: xT consumed, next stores safe

    // epilogue: D[m=l][n=ch]; ch = w*32+nt*16+lm, l = mt*16+quad*4+j -> b64 writes
    #pragma unroll
    for (int nt = 0; nt < 2; ++nt)
      #pragma unroll
      for (int mt = 0; mt < 4; ++mt) {
        short4v p;
        #pragma unroll
        for (int j = 0; j < 4; ++j) {
          float v = __expf(acc[mt][nt][j] + biasE[nt]);
          u16 b = f2b(v);
          sacc[nt] += b2f(b);
          p[j] = (short)b;
        }
        *(short4v*)&ev[w * 32 + nt * 16 + lm][mt * 16 + quad * 4] = p;
      }
    #pragma unroll
    for (int nt = 0; nt < 2; ++nt)
      #pragma unroll
      for (int mt = 0; mt < 4; ++mt) {
        short4v p;
        #pragma unroll
        for (int j = 0; j < 4; ++j)
          p[j] = (short)f2b(acc[mt][nt + 2][j] + biasV[nt]);
        *(short4v*)&ev[128 + w * 32 + nt * 16 + lm][mt * 16 + quad * 4] = p;
      }

    // context MFMAs: read ONLY this wave's own ev rows (same-wave DS order)
    #pragma unroll
    for (int hh = 0; hh < 2; ++hh) {
      int h = w * 2 + hh;
      #pragma unroll
      for (int ks = 0; ks < 2; ++ks) {
        bf16x8 aE = *(const bf16x8*)&ev[h * 16 + lm][ks * 32 + quad * 8];
        bf16x8 bV = *(const bf16x8*)&ev[128 + h * 16 + lm][ks * 32 + quad * 8];
        cacc[hh] = __builtin_amdgcn_mfma_f32_16x16x32_bf16(aE, bV, cacc[hh], 0, 0, 0);
      }
    }
  }

  float* Cn = Cnum2 + slot * 4096;
  #pragma unroll
  for (int hh = 0; hh < 2; ++hh) {
    int h = w * 2 + hh;
    #pragma unroll
    for (int j = 0; j < 4; ++j)
      atomicAdd(&Cn[((n * 8 + h) * 16 + quad * 4 + j) * 16 + lm], cacc[hh][j]);
  }
  #pragma unroll
  for (int nt = 0; nt < 2; ++nt) {
    float s = sacc[nt];
    s += __shfl_xor(s, 16);
    s += __shfl_xor(s, 32);
    if (quad == 0)
      atomicAdd(&S2[slot * 256 + n * 128 + w * 32 + nt * 16 + lm], s);
  }
}

// ---- kB: out = M * softmax_q(Wq x + bq) + br, with M = Wr * ctx built per block.
//      1024 blocks x 2 tiles of 64 cols. ctx LDS buffer is union'd with qT
//      (ctx only needed in prologue) -> LDS 34816 B. PLAIN launch_bounds:
//      round-3's (256,4) min-waves bound clamped VGPRs to 64 and spilled the
//      whole working set to scratch (FETCH 266MB / WRITE 519MB, 252us).
//      Blocks 0 and 512 also emit context_last + CLS_out.
__global__ __launch_bounds__(256) void kB(
    const float* __restrict__ x, const float* __restrict__ CLS,
    const float* __restrict__ Wq, const float* __restrict__ bq,
    const float* __restrict__ Wr, const float* __restrict__ br,
    const float* __restrict__ S2, const float* __restrict__ Cnum2,
    float* __restrict__ out) {
  __shared__ __align__(16) u16 xT[64][136];     // [l][ch] bf16, 17408 B
  __shared__ __align__(16) u16 ubuf[64 * 136];  // prologue: f32 ctxn[4096]; main: qT
  const int t = threadIdx.x;
  const int w = t >> 6, lane = t & 63;
  const int quad = lane >> 4, lm = lane & 15;
  const int bid = blockIdx.x;
  const int n = bid >> 9;                       // 1024 blocks: 512 per batch
  const int l0base = (bid & 511) << 7;          // 128 cols per block
  const int sc = t >> 4, sl4 = t & 15;

  float4 pf[8];
  #pragma unroll
  for (int i = 0; i < 8; ++i)
    pf[i] = *(const float4*)(x + (((size_t)(n * 128 + sc * 8 + i)) << 16) + l0base + sl4 * 4);

  bf16x8 wq[2][4];
  #pragma unroll
  for (int mt = 0; mt < 2; ++mt) {
    int row = (w * 2 + mt) * 16 + lm;
    #pragma unroll
    for (int ks = 0; ks < 4; ++ks)
      wq[mt][ks] = pack8(Wq + row * 128 + ks * 32 + quad * 8);
  }
  float bqv[2][4], brv[2][4];
  #pragma unroll
  for (int mt = 0; mt < 2; ++mt)
    #pragma unroll
    for (int j = 0; j < 4; ++j) {
      bqv[mt][j] = bq[(w * 2 + mt) * 16 + quad * 4 + j];
      brv[mt][j] = br[(w * 2 + mt) * 16 + quad * 4 + j];
    }

  // stage ctx = (sum Cnum slots + CLS num) / (sum S slots + CLS den) into LDS
  float* ctxn = (float*)ubuf;                   // [h*16+k][v] f32, this block's n
  {
    int hk = t >> 1, v0 = (t & 1) * 8;          // hk 0..127, v0 0 or 8
    int hbase = hk & 0x70;                      // h*16
    float ek[4];
    float den = 0.f;
    #pragma unroll
    for (int j = 0; j < 4; ++j) {
      ek[j] = __expf(CLS[(n * 128 + hk) * 4 + j]);
      den += ek[j];
    }
    #pragma unroll
    for (int s = 0; s < 4; ++s) den += S2[s * 256 + n * 128 + hk];
    float inv = 1.f / den;
    float vv[8];
    #pragma unroll
    for (int i = 0; i < 8; ++i) {
      int v = v0 + i;
      float num = 0.f;
      #pragma unroll
      for (int s = 0; s < 4; ++s) num += Cnum2[s * 4096 + (n * 128 + hk) * 16 + v];
      #pragma unroll
      for (int j = 0; j < 4; ++j) num += ek[j] * CLS[(n * 128 + hbase + v) * 4 + j];
      vv[i] = num * inv;
    }
    float4 a = {vv[0], vv[1], vv[2], vv[3]}, b = {vv[4], vv[5], vv[6], vv[7]};
    *(float4*)&ctxn[hk * 16 + v0] = a;
    *(float4*)&ctxn[hk * 16 + v0 + 4] = b;
  }
  __syncthreads();                              // ctxn ready

  // blocks 0 / 512: emit context_last + CLS_out for their n (head 7)
  if ((bid & 511) == 0) {
    {
      int kc = t >> 4, vc = t & 15;             // all 256 threads
      out[OUT_CTX + n * 256 + t] = ctxn[(112 + kc) * 16 + vc];
    }
    if (t < 64) {
      int vc = t >> 2, j = t & 3;
      float den = 0.f, num = 0.f;
      #pragma unroll
      for (int kc = 0; kc < 16; ++kc) {
        float e_ = __expf(CLS[(n * 128 + 112 + kc) * 4 + j]);
        den += e_;
        num += e_ * ctxn[(112 + kc) * 16 + vc];
      }
      out[OUT_CLS + n * 64 + t] = num / den;
    }
  }

  // M-build: mA[mt][ks] = A-frag of M[o][cc] = sum_v Wr[o][h*16+v]*ctx[h][cc&15][v]
  bf16x8 mA[2][4];
  for (int ks = 0; ks < 4; ++ks) {
    int h = 2 * ks + (quad >> 1);
    float4 wrv[2][4];
    #pragma unroll
    for (int mt = 0; mt < 2; ++mt) {
      const float* wp = Wr + ((w * 2 + mt) * 16 + lm) * 128 + h * 16;
      #pragma unroll
      for (int q4 = 0; q4 < 4; ++q4) wrv[mt][q4] = *(const float4*)(wp + q4 * 4);
    }
    short mr0[8], mr1[8];
    #pragma unroll
    for (int jj = 0; jj < 8; ++jj) {
      int k = (quad & 1) * 8 + jj;
      const float4* cp = (const float4*)&ctxn[(h * 16 + k) * 16];
      float4 c0 = cp[0], c1 = cp[1], c2 = cp[2], c3 = cp[3];
      float m0 = dot4(wrv[0][0], c0) + dot4(wrv[0][1], c1) + dot4(wrv[0][2], c2) + dot4(wrv[0][3], c3);
      float m1 = dot4(wrv[1][0], c0) + dot4(wrv[1][1], c1) + dot4(wrv[1][2], c2) + dot4(wrv[1][3], c3);
      mr0[jj] = (short)f2b(m0);
      mr1[jj] = (short)f2b(m1);
    }
    mA[0][ks] = *(bf16x8*)mr0;
    mA[1][ks] = *(bf16x8*)mr1;
  }

  // main loop; tile-0 barrier A orders all ctxn reads before qT reuses the space
  u16 (*qT)[136] = (u16 (*)[136])ubuf;
  floatx4 z4 = {0.f, 0.f, 0.f, 0.f};
  for (int tile = 0; tile < 2; ++tile) {
    int l0 = l0base + tile * 64;
    const float* pff = (const float*)pf;
    #pragma unroll
    for (int r = 0; r < 4; ++r) {
      bf16x8 vx;
      #pragma unroll
      for (int i = 0; i < 8; ++i) vx[i] = (short)f2b(pff[i * 4 + r]);
      *(bf16x8*)&xT[sl4 * 4 + r][sc * 8] = vx;
    }
    if (tile < 1) {
      #pragma unroll
      for (int i = 0; i < 8; ++i)
        pf[i] = *(const float4*)(x + (((size_t)(n * 128 + sc * 8 + i)) << 16) + l0base + 64 + sl4 * 4);
    }
    __syncthreads();                            // A: xT RAW + ubuf WAR

    floatx4 acc[2][4];
    #pragma unroll
    for (int mt = 0; mt < 2; ++mt)
      #pragma unroll
      for (int nt = 0; nt < 4; ++nt) acc[mt][nt] = z4;

    #pragma unroll
    for (int nt = 0; nt < 4; ++nt)
      #pragma unroll
      for (int ks = 0; ks < 4; ++ks) {
        bf16x8 b = *(const bf16x8*)&xT[nt * 16 + lm][ks * 32 + quad * 8];
        #pragma unroll
        for (int mt = 0; mt < 2; ++mt)
          acc[mt][nt] = __builtin_amdgcn_mfma_f32_16x16x32_bf16(wq[mt][ks], b, acc[mt][nt], 0, 0, 0);
      }

    // per-column softmax over the 16 channels of each head (wave-local)
    #pragma unroll
    for (int mt = 0; mt < 2; ++mt) {
      int h = w * 2 + mt;
      #pragma unroll
      for (int nt = 0; nt < 4; ++nt) {
        float e[4];
        float ssum = 0.f;
        #pragma unroll
        for (int j = 0; j < 4; ++j) {
          e[j] = __expf(acc[mt][nt][j] + bqv[mt][j]);
          ssum += e[j];
        }
        ssum += __shfl_xor(ssum, 16);
        ssum += __shfl_xor(ssum, 32);
        float inv = 1.f / ssum;
        short4v p;
        #pragma unroll
        for (int j = 0; j < 4; ++j) p[j] = (short)f2b(e[j] * inv);
        *(short4v*)&qT[nt * 16 + lm][h * 16 + quad * 4] = p;
      }
    }
    __syncthreads();                            // B: all heads' q channels ready

    floatx4 acc2[2][4];
    #pragma unroll
    for (int mt = 0; mt < 2; ++mt)
      #pragma unroll
      for (int nt = 0; nt < 4; ++nt) acc2[mt][nt] = z4;

    #pragma unroll
    for (int nt = 0; nt < 4; ++nt)
      #pragma unroll
      for (int ks = 0; ks < 4; ++ks) {
        bf16x8 b = *(const bf16x8*)&qT[nt * 16 + lm][ks * 32 + quad * 8];
        #pragma unroll
        for (int mt = 0; mt < 2; ++mt)
          acc2[mt][nt] = __builtin_amdgcn_mfma_f32_16x16x32_bf16(mA[mt][ks], b, acc2[mt][nt], 0, 0, 0);
      }

    #pragma unroll
    for (int mt = 0; mt < 2; ++mt)
      #pragma unroll
      for (int j = 0; j < 4; ++j) {
        int R = (w * 2 + mt) * 16 + quad * 4 + j;
        #pragma unroll
        for (int nt = 0; nt < 4; ++nt)
          out[(((size_t)(n * 128 + R)) << 16) + l0 + nt * 16 + lm] = acc2[mt][nt][j] + brv[mt][j];
      }
  }
}

extern "C" void kernel_launch(void* const* d_in, const int* in_sizes, int n_in,
                              void* d_out, int out_size, void* d_ws, size_t ws_size,
                              hipStream_t stream) {
  const float* x   = (const float*)d_in[0];
  const float* CLS = (const float*)d_in[1];
  const float* Wk  = (const float*)d_in[2];
  const float* bk  = (const float*)d_in[3];
  const float* Wq  = (const float*)d_in[4];
  const float* bq  = (const float*)d_in[5];
  const float* Wv  = (const float*)d_in[6];
  const float* bv  = (const float*)d_in[7];
  const float* Wr  = (const float*)d_in[8];
  const float* br  = (const float*)d_in[9];
  float* out = (float*)d_out;
  char* ws = (char*)d_ws;
  float* S2    = (float*)(ws + 0);        // 4 slots x 256 f32  = 4096 B
  float* Cnum2 = (float*)(ws + 4096);     // 4 slots x 4096 f32 = 65536 B

  hipMemsetAsync(ws, 0, 69632, stream);
  kA<<<512, 256, 0, stream>>>(x, Wk, bk, Wv, bv, S2, Cnum2);
  kB<<<1024, 256, 0, stream>>>(x, CLS, Wq, bq, Wr, br, S2, Cnum2, out);
}